// Round 3
// baseline (163.960 us; speedup 1.0000x reference)
//
#include <hip/hip_runtime.h>

// Problem constants (match reference: B=16, S=4096, D=128)
#define BB   16
#define SS   4096
#define DD   128
#define NCH  256            // chunks per batch
#define TT   (SS / NCH)     // 16 steps per chunk
#define WPB  4              // waves (=chunks) per block
#define NTHR 256

// pass2 two-level scan geometry
#define DT   16             // d's per pass2 block
#define SUBS 16             // sub-ranges per (b,d)
#define CPS  (NCH / SUBS)   // 16 chunks per sub-range

#define LN_EPS  1e-5f
#define REC_EPS 1e-8f

__device__ __forceinline__ float fast_rcp(float x) { return __builtin_amdgcn_rcpf(x); }
__device__ __forceinline__ float sigm(float x) { return fast_rcp(1.0f + __expf(-x)); }

// pack (decay, e) as bf16 pair: lo16 = decay, hi16 = e (round-half-up)
__device__ __forceinline__ unsigned pack_de(float d, float e) {
    unsigned ud = (__float_as_uint(d) + 0x8000u) >> 16;
    unsigned ue = (__float_as_uint(e) + 0x8000u) & 0xFFFF0000u;
    return ue | ud;
}
__device__ __forceinline__ float de_lo(unsigned u) { return __uint_as_float(u << 16); }
__device__ __forceinline__ float de_hi(unsigned u) { return __uint_as_float(u & 0xFFFF0000u); }

// DPP shifted copy with 0-fill (bound_ctrl=1). CTRL is a compile-time const.
template<int CTRL>
__device__ __forceinline__ float dpp_mov0(float x) {
    return __int_as_float(
        __builtin_amdgcn_update_dpp(0, __float_as_int(x), CTRL, 0xF, 0xF, true));
}

// Full 64-lane wave sum of two values, VALU-only (no LDS pipe):
// row_shr:1/2/4/8 reduce within 16-lane rows; row_bcast:15/31 cross rows;
// lane 63 holds the total; readlane broadcasts it.
__device__ __forceinline__ void wave_red2(float& a, float& b) {
    a += dpp_mov0<0x111>(a); b += dpp_mov0<0x111>(b);   // row_shr:1
    a += dpp_mov0<0x112>(a); b += dpp_mov0<0x112>(b);   // row_shr:2
    a += dpp_mov0<0x114>(a); b += dpp_mov0<0x114>(b);   // row_shr:4
    a += dpp_mov0<0x118>(a); b += dpp_mov0<0x118>(b);   // row_shr:8
    a += dpp_mov0<0x142>(a); b += dpp_mov0<0x142>(b);   // row_bcast:15
    a += dpp_mov0<0x143>(a); b += dpp_mov0<0x143>(b);   // row_bcast:31
    a = __int_as_float(__builtin_amdgcn_readlane(__float_as_int(a), 63));
    b = __int_as_float(__builtin_amdgcn_readlane(__float_as_int(b), 63));
}

// ---------------------------------------------------------------------------
// Pass 1: per-chunk transfer functions + bf16 (decay, exp(c)) side-band.
// One 64-lane wave per chunk; 2 d's per lane.
// ---------------------------------------------------------------------------
__global__ __launch_bounds__(NTHR, 4) void pass1_kernel(
    const float* __restrict__ C, const float* __restrict__ V, const float* __restrict__ W,
    const float* __restrict__ enc, const float* __restrict__ tmod, const float* __restrict__ cmod,
    unsigned* __restrict__ DE,
    float* __restrict__ Pbuf, float* __restrict__ Qbuf,
    float* __restrict__ PaBuf, float* __restrict__ QaBuf,
    float2* __restrict__ MEbuf)
{
    const int wv   = threadIdx.x >> 6;
    const int lane = threadIdx.x & 63;
    const int gc   = blockIdx.x * WPB + wv;        // global chunk id = b*NCH + ch
    const int b    = gc >> 8;                      // / NCH (256)
    const int ch   = gc & (NCH - 1);
    const int d2   = lane << 1;

    const float2 tm = *(const float2*)(tmod + d2);
    const float2 cm = *(const float2*)(cmod + d2);
    const float2 ec = *(const float2*)(enc + b * DD + d2);
    float2 ctx;
    ctx.x = sigm(ec.x * cm.x) * ec.x;
    ctx.y = sigm(ec.y * cm.y) * ec.y;

    float2 P = make_float2(1.f, 1.f);
    float2 Q = make_float2(0.f, 0.f);
    float pa = 1.f, qa = 0.f;

    const int t0 = ch * TT;
    const size_t base = ((size_t)b * SS + t0) * DD + d2;
    const float2* Cp = (const float2*)(C + base);
    const float2* Vp = (const float2*)(V + base);
    const float2* Wp = (const float2*)(W + base);
    uint2* DEp = (uint2*)(DE + base);

#pragma unroll 4
    for (int t = 0; t < TT; ++t) {
        const float2 c2 = Cp[t * (DD / 2)];
        const float2 v2 = Vp[t * (DD / 2)];
        const float2 w2 = Wp[t * (DD / 2)];
        float2 dec, e2;
        dec.x = sigm(w2.x * tm.x); dec.y = sigm(w2.y * tm.y);
        e2.x = __expf(c2.x); e2.y = __expf(c2.y);

        uint2 u;
        u.x = pack_de(dec.x, e2.x); u.y = pack_de(dec.y, e2.y);
        DEp[t * (DD / 2)] = u;

        Q.x = dec.x * Q.x + (e2.x * v2.x + ctx.x);
        Q.y = dec.y * Q.y + (e2.y * v2.y + ctx.y);
        P.x *= dec.x; P.y *= dec.y;

        float sd = dec.x + dec.y;
        float se = e2.x + e2.y;
        wave_red2(sd, se);
        const float mt = sd * (1.0f / DD);
        pa *= mt;
        qa = mt * qa + se;
        if (lane == 0) MEbuf[(size_t)b * SS + t0 + t] = make_float2(mt, se);
    }

    *(float2*)(Pbuf + (size_t)gc * DD + d2) = P;
    *(float2*)(Qbuf + (size_t)gc * DD + d2) = Q;
    if (lane == 0) { PaBuf[gc] = pa; QaBuf[gc] = qa; }
}

// ---------------------------------------------------------------------------
// Pass 2: two-level scan of chunk transfer functions -> chunk-entry states.
// ---------------------------------------------------------------------------
__global__ __launch_bounds__(256) void pass2_kernel(
    const float* __restrict__ Pbuf, const float* __restrict__ Qbuf,
    const float* __restrict__ PaBuf, const float* __restrict__ QaBuf,
    float* __restrict__ bst0, float* __restrict__ a0)
{
    const int b   = blockIdx.x >> 3;
    const int dt  = blockIdx.x & 7;
    const int tid = threadIdx.x;
    const int dl  = tid & (DT - 1);
    const int sub = tid >> 4;
    const int d   = dt * DT + dl;

    __shared__ float cP[SUBS][DT], cQ[SUBS][DT], ent[SUBS][DT];
    __shared__ float sPa[NCH], sQa[NCH];

    // sweep 1: local composite over this thread's 16 chunks (kept in regs)
    const int ch0 = sub * CPS;
    const size_t base = ((size_t)b * NCH + ch0) * DD + d;
    float Pr[CPS], Qr[CPS];
    float p = 1.f, q = 0.f;
#pragma unroll
    for (int i = 0; i < CPS; ++i) {
        Pr[i] = Pbuf[base + (size_t)i * DD];
        Qr[i] = Qbuf[base + (size_t)i * DD];
        q = Pr[i] * q + Qr[i];
        p = Pr[i] * p;
    }
    cP[sub][dl] = p; cQ[sub][dl] = q;
    __syncthreads();

    // combine: entry state per sub-range (init state = 0)
    if (tid < DT) {
        float s = 0.f;
#pragma unroll
        for (int sb = 0; sb < SUBS; ++sb) {
            ent[sb][tid] = s;
            s = cP[sb][tid] * s + cQ[sb][tid];
        }
    }
    __syncthreads();

    // sweep 2: replay from entry state, write bst0
    float s = ent[sub][dl];
#pragma unroll
    for (int i = 0; i < CPS; ++i) {
        bst0[base + (size_t)i * DD] = s;
        s = Pr[i] * s + Qr[i];
    }

    // scalar a-scan (one tile of blocks only; block-uniform branch)
    if (dt == 0) {
        float pa = PaBuf[b * NCH + tid];
        float qa = QaBuf[b * NCH + tid];
#pragma unroll
        for (int off = 1; off < NCH; off <<= 1) {
            sPa[tid] = pa; sQa[tid] = qa;
            __syncthreads();
            if (tid >= off) {
                const float pp = sPa[tid - off], qq = sQa[tid - off];
                qa = pa * qq + qa;
                pa = pa * pp;
            }
            __syncthreads();
        }
        sQa[tid] = qa;
        __syncthreads();
        a0[b * NCH + tid] = (tid == 0) ? 0.f : sQa[tid - 1];
    }
}

// ---------------------------------------------------------------------------
// Pass 3: replay each chunk from its entry state using the bf16 DE side-band;
// fused LayerNorm; one wave per chunk, DPP reductions.
// ---------------------------------------------------------------------------
__global__ __launch_bounds__(NTHR, 4) void pass3_kernel(
    const float* __restrict__ V, const unsigned* __restrict__ DE,
    const float* __restrict__ enc, const float* __restrict__ cmod,
    const float* __restrict__ lnw, const float* __restrict__ lnb,
    const float* __restrict__ bst0, const float* __restrict__ a0,
    const float2* __restrict__ MEbuf,
    float* __restrict__ out)
{
    const int wv   = threadIdx.x >> 6;
    const int lane = threadIdx.x & 63;
    const int gc   = blockIdx.x * WPB + wv;
    const int b    = gc >> 8;
    const int ch   = gc & (NCH - 1);
    const int d2   = lane << 1;

    const float2 cm = *(const float2*)(cmod + d2);
    const float2 ec = *(const float2*)(enc + b * DD + d2);
    float2 ctx;
    ctx.x = sigm(ec.x * cm.x) * ec.x;
    ctx.y = sigm(ec.y * cm.y) * ec.y;
    const float2 gw = *(const float2*)(lnw + d2);
    const float2 gb = *(const float2*)(lnb + d2);

    float2 bst = *(const float2*)(bst0 + (size_t)gc * DD + d2);
    float a = a0[gc];

    const int t0 = ch * TT;
    const size_t base = ((size_t)b * SS + t0) * DD + d2;
    const float2* Vp  = (const float2*)(V + base);
    const uint2*  DEp = (const uint2*)(DE + base);
    float2* Op = (float2*)(out + base);
    const float2* MEp = MEbuf + (size_t)b * SS + t0;

#pragma unroll 4
    for (int t = 0; t < TT; ++t) {
        const float2 v2 = Vp[t * (DD / 2)];
        const uint2  u  = DEp[t * (DD / 2)];
        const float2 me = MEp[t];

        a = me.x * a + me.y;
        bst.x = de_lo(u.x) * bst.x + (de_hi(u.x) * v2.x + ctx.x);
        bst.y = de_lo(u.y) * bst.y + (de_hi(u.y) * v2.y + ctx.y);

        const float inva = fast_rcp(a + REC_EPS);
        float2 o;
        o.x = bst.x * inva; o.y = bst.y * inva;

        float s1 = o.x + o.y;
        float s2 = o.x * o.x + o.y * o.y;
        wave_red2(s1, s2);
        const float mu  = s1 * (1.0f / DD);
        const float var = s2 * (1.0f / DD) - mu * mu;
        const float rs  = rsqrtf(var + LN_EPS);

        float2 r;
        r.x = (o.x - mu) * rs * gw.x + gb.x;
        r.y = (o.y - mu) * rs * gw.y + gb.y;
        Op[t * (DD / 2)] = r;
    }
}

extern "C" void kernel_launch(void* const* d_in, const int* in_sizes, int n_in,
                              void* d_out, int out_size, void* d_ws, size_t ws_size,
                              hipStream_t stream)
{
    const float* C    = (const float*)d_in[0];
    const float* V    = (const float*)d_in[1];
    const float* W    = (const float*)d_in[2];
    const float* enc  = (const float*)d_in[3];
    const float* tmod = (const float*)d_in[4];
    const float* cmod = (const float*)d_in[5];
    const float* lnw  = (const float*)d_in[6];
    const float* lnb  = (const float*)d_in[7];
    float* out = (float*)d_out;

    // Workspace layout: DE (32 MB) + scan buffers (~7 MB)
    float* ws    = (float*)d_ws;
    unsigned* DEbuf = (unsigned*)ws;                      // BB*SS*DD uints
    float* Pbuf  = ws    + (size_t)BB * SS * DD;          // BB*NCH*DD
    float* Qbuf  = Pbuf  + (size_t)BB * NCH * DD;
    float* bst0  = Qbuf  + (size_t)BB * NCH * DD;
    float2* MEbuf = (float2*)(bst0 + (size_t)BB * NCH * DD);  // BB*SS float2
    float* PaBuf = (float*)(MEbuf + (size_t)BB * SS);         // BB*NCH
    float* QaBuf = PaBuf + (size_t)BB * NCH;
    float* a0Buf = QaBuf + (size_t)BB * NCH;

    const int nblk = BB * NCH / WPB;   // 1024
    pass1_kernel<<<nblk, NTHR, 0, stream>>>(C, V, W, enc, tmod, cmod, DEbuf,
                                            Pbuf, Qbuf, PaBuf, QaBuf, MEbuf);
    pass2_kernel<<<BB * 8, 256, 0, stream>>>(Pbuf, Qbuf, PaBuf, QaBuf, bst0, a0Buf);
    pass3_kernel<<<nblk, NTHR, 0, stream>>>(V, DEbuf, enc, cmod, lnw, lnb,
                                            bst0, a0Buf, MEbuf, out);
}

// Round 4
// 161.161 us; speedup vs baseline: 1.0174x; 1.0174x over previous
//
#include <hip/hip_runtime.h>

// Problem constants (match reference: B=16, S=4096, D=128)
#define BB   16
#define SS   4096
#define DD   128
#define NCH  256            // chunks per batch
#define TT   (SS / NCH)     // 16 steps per chunk
#define WPB  4              // waves (=chunks) per block
#define NTHR 256

// pass2 two-level scan geometry
#define DT   16             // d's per pass2 block
#define SUBS 16             // sub-ranges per (b,d)
#define CPS  (NCH / SUBS)   // 16 chunks per sub-range

#define LN_EPS  1e-5f
#define REC_EPS 1e-8f

__device__ __forceinline__ float fast_rcp(float x) { return __builtin_amdgcn_rcpf(x); }
__device__ __forceinline__ float sigm(float x) { return fast_rcp(1.0f + __expf(-x)); }

// pack (decay, e) as bf16 pair: lo16 = decay, hi16 = e (round-half-up)
__device__ __forceinline__ unsigned pack_de(float d, float e) {
    unsigned ud = (__float_as_uint(d) + 0x8000u) >> 16;
    unsigned ue = (__float_as_uint(e) + 0x8000u) & 0xFFFF0000u;
    return ue | ud;
}
__device__ __forceinline__ float de_lo(unsigned u) { return __uint_as_float(u << 16); }
__device__ __forceinline__ float de_hi(unsigned u) { return __uint_as_float(u & 0xFFFF0000u); }

// DPP shifted copy with 0-fill (bound_ctrl=1). CTRL is a compile-time const.
template<int CTRL>
__device__ __forceinline__ float dpp_mov0(float x) {
    return __int_as_float(
        __builtin_amdgcn_update_dpp(0, __float_as_int(x), CTRL, 0xF, 0xF, true));
}

// Full 64-lane wave sum of two values, VALU-only (verified on HW in R3).
__device__ __forceinline__ void wave_red2(float& a, float& b) {
    a += dpp_mov0<0x111>(a); b += dpp_mov0<0x111>(b);   // row_shr:1
    a += dpp_mov0<0x112>(a); b += dpp_mov0<0x112>(b);   // row_shr:2
    a += dpp_mov0<0x114>(a); b += dpp_mov0<0x114>(b);   // row_shr:4
    a += dpp_mov0<0x118>(a); b += dpp_mov0<0x118>(b);   // row_shr:8
    a += dpp_mov0<0x142>(a); b += dpp_mov0<0x142>(b);   // row_bcast:15
    a += dpp_mov0<0x143>(a); b += dpp_mov0<0x143>(b);   // row_bcast:31
    a = __int_as_float(__builtin_amdgcn_readlane(__float_as_int(a), 63));
    b = __int_as_float(__builtin_amdgcn_readlane(__float_as_int(b), 63));
}

// ---------------------------------------------------------------------------
// Pass 1: whole chunk loaded to registers up front (one HBM round trip/wave),
// then 16 fully-unrolled steps from registers. One wave per chunk, 2 d/lane.
// ---------------------------------------------------------------------------
__global__ __launch_bounds__(NTHR, 2) void pass1_kernel(
    const float* __restrict__ C, const float* __restrict__ V, const float* __restrict__ W,
    const float* __restrict__ enc, const float* __restrict__ tmod, const float* __restrict__ cmod,
    unsigned* __restrict__ DE,
    float* __restrict__ Pbuf, float* __restrict__ Qbuf,
    float* __restrict__ PaBuf, float* __restrict__ QaBuf,
    float2* __restrict__ MEbuf)
{
    const int wv   = threadIdx.x >> 6;
    const int lane = threadIdx.x & 63;
    const int gc   = blockIdx.x * WPB + wv;        // global chunk id = b*NCH + ch
    const int b    = gc >> 8;                      // / NCH (256)
    const int ch   = gc & (NCH - 1);
    const int d2   = lane << 1;

    const int t0 = ch * TT;
    const size_t base = ((size_t)b * SS + t0) * DD + d2;
    const float2* Cp = (const float2*)(C + base);
    const float2* Vp = (const float2*)(V + base);
    const float2* Wp = (const float2*)(W + base);
    uint2* DEp = (uint2*)(DE + base);

    // ---- bulk load: 48 independent loads, all in flight at once ----
    float2 cR[TT], wR[TT], vR[TT];
#pragma unroll
    for (int t = 0; t < TT; ++t) cR[t] = Cp[t * (DD / 2)];
#pragma unroll
    for (int t = 0; t < TT; ++t) wR[t] = Wp[t * (DD / 2)];
#pragma unroll
    for (int t = 0; t < TT; ++t) vR[t] = Vp[t * (DD / 2)];

    const float2 tm = *(const float2*)(tmod + d2);
    const float2 cm = *(const float2*)(cmod + d2);
    const float2 ec = *(const float2*)(enc + b * DD + d2);
    float2 ctx;
    ctx.x = sigm(ec.x * cm.x) * ec.x;
    ctx.y = sigm(ec.y * cm.y) * ec.y;

    float2 P = make_float2(1.f, 1.f);
    float2 Q = make_float2(0.f, 0.f);
    float pa = 1.f, qa = 0.f;
    float mkeep = 0.f, ekeep = 0.f;

#pragma unroll
    for (int t = 0; t < TT; ++t) {
        float2 dec, e2;
        dec.x = sigm(wR[t].x * tm.x); dec.y = sigm(wR[t].y * tm.y);
        e2.x = __expf(cR[t].x); e2.y = __expf(cR[t].y);

        uint2 u;
        u.x = pack_de(dec.x, e2.x); u.y = pack_de(dec.y, e2.y);
        DEp[t * (DD / 2)] = u;

        Q.x = dec.x * Q.x + (e2.x * vR[t].x + ctx.x);
        Q.y = dec.y * Q.y + (e2.y * vR[t].y + ctx.y);
        P.x *= dec.x; P.y *= dec.y;

        float sd = dec.x + dec.y;
        float se = e2.x + e2.y;
        wave_red2(sd, se);
        const float mt = sd * (1.0f / DD);
        pa *= mt;
        qa = mt * qa + se;
        if (lane == t) { mkeep = mt; ekeep = se; }   // capture, store once at end
    }

    *(float2*)(Pbuf + (size_t)gc * DD + d2) = P;
    *(float2*)(Qbuf + (size_t)gc * DD + d2) = Q;
    if (lane < TT) MEbuf[(size_t)b * SS + t0 + lane] = make_float2(mkeep, ekeep);
    if (lane == 0) { PaBuf[gc] = pa; QaBuf[gc] = qa; }
}

// ---------------------------------------------------------------------------
// Pass 2: two-level scan of chunk transfer functions -> chunk-entry states.
// ---------------------------------------------------------------------------
__global__ __launch_bounds__(256) void pass2_kernel(
    const float* __restrict__ Pbuf, const float* __restrict__ Qbuf,
    const float* __restrict__ PaBuf, const float* __restrict__ QaBuf,
    float* __restrict__ bst0, float* __restrict__ a0)
{
    const int b   = blockIdx.x >> 3;
    const int dt  = blockIdx.x & 7;
    const int tid = threadIdx.x;
    const int dl  = tid & (DT - 1);
    const int sub = tid >> 4;
    const int d   = dt * DT + dl;

    __shared__ float cP[SUBS][DT], cQ[SUBS][DT], ent[SUBS][DT];
    __shared__ float sPa[NCH], sQa[NCH];

    // sweep 1: local composite over this thread's 16 chunks (kept in regs)
    const int ch0 = sub * CPS;
    const size_t base = ((size_t)b * NCH + ch0) * DD + d;
    float Pr[CPS], Qr[CPS];
    float p = 1.f, q = 0.f;
#pragma unroll
    for (int i = 0; i < CPS; ++i) {
        Pr[i] = Pbuf[base + (size_t)i * DD];
        Qr[i] = Qbuf[base + (size_t)i * DD];
        q = Pr[i] * q + Qr[i];
        p = Pr[i] * p;
    }
    cP[sub][dl] = p; cQ[sub][dl] = q;
    __syncthreads();

    // combine: entry state per sub-range (init state = 0)
    if (tid < DT) {
        float s = 0.f;
#pragma unroll
        for (int sb = 0; sb < SUBS; ++sb) {
            ent[sb][tid] = s;
            s = cP[sb][tid] * s + cQ[sb][tid];
        }
    }
    __syncthreads();

    // sweep 2: replay from entry state, write bst0
    float s = ent[sub][dl];
#pragma unroll
    for (int i = 0; i < CPS; ++i) {
        bst0[base + (size_t)i * DD] = s;
        s = Pr[i] * s + Qr[i];
    }

    // scalar a-scan (one tile of blocks only; block-uniform branch)
    if (dt == 0) {
        float pa = PaBuf[b * NCH + tid];
        float qa = QaBuf[b * NCH + tid];
#pragma unroll
        for (int off = 1; off < NCH; off <<= 1) {
            sPa[tid] = pa; sQa[tid] = qa;
            __syncthreads();
            if (tid >= off) {
                const float pp = sPa[tid - off], qq = sQa[tid - off];
                qa = pa * qq + qa;
                pa = pa * pp;
            }
            __syncthreads();
        }
        sQa[tid] = qa;
        __syncthreads();
        a0[b * NCH + tid] = (tid == 0) ? 0.f : sQa[tid - 1];
    }
}

// ---------------------------------------------------------------------------
// Pass 3: whole chunk (V + DE side-band) to registers up front, replay from
// entry state, fused LayerNorm. ME scalars broadcast via readlane.
// ---------------------------------------------------------------------------
__global__ __launch_bounds__(NTHR, 2) void pass3_kernel(
    const float* __restrict__ V, const unsigned* __restrict__ DE,
    const float* __restrict__ enc, const float* __restrict__ cmod,
    const float* __restrict__ lnw, const float* __restrict__ lnb,
    const float* __restrict__ bst0, const float* __restrict__ a0,
    const float2* __restrict__ MEbuf,
    float* __restrict__ out)
{
    const int wv   = threadIdx.x >> 6;
    const int lane = threadIdx.x & 63;
    const int gc   = blockIdx.x * WPB + wv;
    const int b    = gc >> 8;
    const int ch   = gc & (NCH - 1);
    const int d2   = lane << 1;

    const int t0 = ch * TT;
    const size_t base = ((size_t)b * SS + t0) * DD + d2;
    const float2* Vp  = (const float2*)(V + base);
    const uint2*  DEp = (const uint2*)(DE + base);
    float2* Op = (float2*)(out + base);

    // ---- bulk load: 32 independent loads + ME + state, all in flight ----
    float2 vR[TT]; uint2 deR[TT];
#pragma unroll
    for (int t = 0; t < TT; ++t) deR[t] = DEp[t * (DD / 2)];
#pragma unroll
    for (int t = 0; t < TT; ++t) vR[t] = Vp[t * (DD / 2)];
    const float2 me = MEbuf[(size_t)b * SS + t0 + (lane & (TT - 1))];

    const float2 cm = *(const float2*)(cmod + d2);
    const float2 ec = *(const float2*)(enc + b * DD + d2);
    float2 ctx;
    ctx.x = sigm(ec.x * cm.x) * ec.x;
    ctx.y = sigm(ec.y * cm.y) * ec.y;
    const float2 gw = *(const float2*)(lnw + d2);
    const float2 gb = *(const float2*)(lnb + d2);

    float2 bst = *(const float2*)(bst0 + (size_t)gc * DD + d2);
    float a = a0[gc];

#pragma unroll
    for (int t = 0; t < TT; ++t) {
        const float mt = __int_as_float(__builtin_amdgcn_readlane(__float_as_int(me.x), t));
        const float et = __int_as_float(__builtin_amdgcn_readlane(__float_as_int(me.y), t));

        a = mt * a + et;
        bst.x = de_lo(deR[t].x) * bst.x + (de_hi(deR[t].x) * vR[t].x + ctx.x);
        bst.y = de_lo(deR[t].y) * bst.y + (de_hi(deR[t].y) * vR[t].y + ctx.y);

        const float inva = fast_rcp(a + REC_EPS);
        float2 o;
        o.x = bst.x * inva; o.y = bst.y * inva;

        float s1 = o.x + o.y;
        float s2 = o.x * o.x + o.y * o.y;
        wave_red2(s1, s2);
        const float mu  = s1 * (1.0f / DD);
        const float var = s2 * (1.0f / DD) - mu * mu;
        const float rs  = rsqrtf(var + LN_EPS);

        float2 r;
        r.x = (o.x - mu) * rs * gw.x + gb.x;
        r.y = (o.y - mu) * rs * gw.y + gb.y;
        Op[t * (DD / 2)] = r;
    }
}

extern "C" void kernel_launch(void* const* d_in, const int* in_sizes, int n_in,
                              void* d_out, int out_size, void* d_ws, size_t ws_size,
                              hipStream_t stream)
{
    const float* C    = (const float*)d_in[0];
    const float* V    = (const float*)d_in[1];
    const float* W    = (const float*)d_in[2];
    const float* enc  = (const float*)d_in[3];
    const float* tmod = (const float*)d_in[4];
    const float* cmod = (const float*)d_in[5];
    const float* lnw  = (const float*)d_in[6];
    const float* lnb  = (const float*)d_in[7];
    float* out = (float*)d_out;

    // Workspace layout: DE (32 MB) + scan buffers (~7 MB)
    float* ws    = (float*)d_ws;
    unsigned* DEbuf = (unsigned*)ws;                      // BB*SS*DD uints
    float* Pbuf  = ws    + (size_t)BB * SS * DD;          // BB*NCH*DD
    float* Qbuf  = Pbuf  + (size_t)BB * NCH * DD;
    float* bst0  = Qbuf  + (size_t)BB * NCH * DD;
    float2* MEbuf = (float2*)(bst0 + (size_t)BB * NCH * DD);  // BB*SS float2
    float* PaBuf = (float*)(MEbuf + (size_t)BB * SS);         // BB*NCH
    float* QaBuf = PaBuf + (size_t)BB * NCH;
    float* a0Buf = QaBuf + (size_t)BB * NCH;

    const int nblk = BB * NCH / WPB;   // 1024
    pass1_kernel<<<nblk, NTHR, 0, stream>>>(C, V, W, enc, tmod, cmod, DEbuf,
                                            Pbuf, Qbuf, PaBuf, QaBuf, MEbuf);
    pass2_kernel<<<BB * 8, 256, 0, stream>>>(Pbuf, Qbuf, PaBuf, QaBuf, bst0, a0Buf);
    pass3_kernel<<<nblk, NTHR, 0, stream>>>(V, DEbuf, enc, cmod, lnw, lnb,
                                            bst0, a0Buf, MEbuf, out);
}

// Round 5
// 158.901 us; speedup vs baseline: 1.0318x; 1.0142x over previous
//
#include <hip/hip_runtime.h>

// Problem constants (match reference: B=16, S=4096, D=128)
#define BB   16
#define SS   4096
#define DD   128
#define NCH  256            // chunks per batch
#define TT   (SS / NCH)     // 16 steps per chunk
#define WPB  4              // waves (=chunks) per block
#define NTHR 256

// pass2 two-level scan geometry
#define DT   16             // d's per pass2 block
#define SUBS 16             // sub-ranges per (b,d)
#define CPS  (NCH / SUBS)   // 16 chunks per sub-range

#define LN_EPS  1e-5f
#define REC_EPS 1e-8f

__device__ __forceinline__ float fast_rcp(float x) { return __builtin_amdgcn_rcpf(x); }
__device__ __forceinline__ float sigm(float x) { return fast_rcp(1.0f + __expf(-x)); }

// pack two floats as bf16 pair: lo16 = a, hi16 = b (round-half-up in magnitude)
__device__ __forceinline__ unsigned pack2(float a, float b) {
    unsigned ua = (__float_as_uint(a) + 0x8000u) >> 16;
    unsigned ub = (__float_as_uint(b) + 0x8000u) & 0xFFFF0000u;
    return ub | ua;
}
__device__ __forceinline__ float up_lo(unsigned u) { return __uint_as_float(u << 16); }
__device__ __forceinline__ float up_hi(unsigned u) { return __uint_as_float(u & 0xFFFF0000u); }

// DPP shifted copy with 0-fill (bound_ctrl=1). CTRL is a compile-time const.
template<int CTRL>
__device__ __forceinline__ float dpp_mov0(float x) {
    return __int_as_float(
        __builtin_amdgcn_update_dpp(0, __float_as_int(x), CTRL, 0xF, 0xF, true));
}

// Full 64-lane wave sum of two values, VALU-only (verified on HW in R3).
__device__ __forceinline__ void wave_red2(float& a, float& b) {
    a += dpp_mov0<0x111>(a); b += dpp_mov0<0x111>(b);   // row_shr:1
    a += dpp_mov0<0x112>(a); b += dpp_mov0<0x112>(b);   // row_shr:2
    a += dpp_mov0<0x114>(a); b += dpp_mov0<0x114>(b);   // row_shr:4
    a += dpp_mov0<0x118>(a); b += dpp_mov0<0x118>(b);   // row_shr:8
    a += dpp_mov0<0x142>(a); b += dpp_mov0<0x142>(b);   // row_bcast:15
    a += dpp_mov0<0x143>(a); b += dpp_mov0<0x143>(b);   // row_bcast:31
    a = __int_as_float(__builtin_amdgcn_readlane(__float_as_int(a), 63));
    b = __int_as_float(__builtin_amdgcn_readlane(__float_as_int(b), 63));
}

// Compiler memory barrier: loads above CANNOT sink below (forces the whole
// staged batch to be issued and live in VGPRs before compute starts).
#define LOAD_FENCE() asm volatile("" ::: "memory")

// ---------------------------------------------------------------------------
// Pass 1: stage the whole chunk (C,W,V interleaved, 48 loads) behind a load
// fence -> all loads in flight at once; compute 16 steps from registers.
// Packs (decay, T = e*v + ctx) bf16 side-band; P/Q computed from the
// QUANTIZED values so pass3's replay matches the scan exactly.
// ---------------------------------------------------------------------------
__global__ __launch_bounds__(NTHR, 2) void pass1_kernel(
    const float* __restrict__ C, const float* __restrict__ V, const float* __restrict__ W,
    const float* __restrict__ enc, const float* __restrict__ tmod, const float* __restrict__ cmod,
    unsigned* __restrict__ DTb,
    float* __restrict__ Pbuf, float* __restrict__ Qbuf,
    float* __restrict__ PaBuf, float* __restrict__ QaBuf,
    float2* __restrict__ MEbuf)
{
    const int wv   = threadIdx.x >> 6;
    const int lane = threadIdx.x & 63;
    const int gc   = blockIdx.x * WPB + wv;        // global chunk id = b*NCH + ch
    const int b    = gc >> 8;                      // / NCH (256)
    const int ch   = gc & (NCH - 1);
    const int d2   = lane << 1;

    const int t0 = ch * TT;
    const size_t base = ((size_t)b * SS + t0) * DD + d2;
    const float2* Cp = (const float2*)(C + base);
    const float2* Vp = (const float2*)(V + base);
    const float2* Wp = (const float2*)(W + base);
    uint2* DTp = (uint2*)(DTb + base);

    const float2 tm = *(const float2*)(tmod + d2);
    const float2 cm = *(const float2*)(cmod + d2);
    const float2 ec = *(const float2*)(enc + b * DD + d2);

    // ---- staged bulk load: 48 independent loads, all in flight ----
    float2 cR[TT], wR[TT], vR[TT];
#pragma unroll
    for (int t = 0; t < TT; ++t) {
        cR[t] = Cp[t * (DD / 2)];
        wR[t] = Wp[t * (DD / 2)];
        vR[t] = Vp[t * (DD / 2)];
    }
    LOAD_FENCE();

    float2 ctx;
    ctx.x = sigm(ec.x * cm.x) * ec.x;
    ctx.y = sigm(ec.y * cm.y) * ec.y;

    float2 P = make_float2(1.f, 1.f);
    float2 Q = make_float2(0.f, 0.f);
    float pa = 1.f, qa = 0.f;
    float mkeep = 0.f, ekeep = 0.f;

#pragma unroll
    for (int t = 0; t < TT; ++t) {
        float2 dec, e2, T2;
        dec.x = sigm(wR[t].x * tm.x); dec.y = sigm(wR[t].y * tm.y);
        e2.x = __expf(cR[t].x); e2.y = __expf(cR[t].y);
        T2.x = e2.x * vR[t].x + ctx.x;
        T2.y = e2.y * vR[t].y + ctx.y;

        uint2 u;
        u.x = pack2(dec.x, T2.x); u.y = pack2(dec.y, T2.y);
        DTp[t * (DD / 2)] = u;

        // quantized values for the scan (exact match with pass3 replay)
        const float dqx = up_lo(u.x), dqy = up_lo(u.y);
        const float tqx = up_hi(u.x), tqy = up_hi(u.y);
        Q.x = dqx * Q.x + tqx;
        Q.y = dqy * Q.y + tqy;
        P.x *= dqx; P.y *= dqy;

        float sd = dec.x + dec.y;
        float se = e2.x + e2.y;
        wave_red2(sd, se);
        const float mt = sd * (1.0f / DD);
        pa *= mt;
        qa = mt * qa + se;
        if (lane == t) { mkeep = mt; ekeep = se; }   // capture, store once at end
    }

    *(float2*)(Pbuf + (size_t)gc * DD + d2) = P;
    *(float2*)(Qbuf + (size_t)gc * DD + d2) = Q;
    if (lane < TT) MEbuf[(size_t)b * SS + t0 + lane] = make_float2(mkeep, ekeep);
    if (lane == 0) { PaBuf[gc] = pa; QaBuf[gc] = qa; }
}

// ---------------------------------------------------------------------------
// Pass 2: two-level scan of chunk transfer functions -> chunk-entry states.
// ---------------------------------------------------------------------------
__global__ __launch_bounds__(256) void pass2_kernel(
    const float* __restrict__ Pbuf, const float* __restrict__ Qbuf,
    const float* __restrict__ PaBuf, const float* __restrict__ QaBuf,
    float* __restrict__ bst0, float* __restrict__ a0)
{
    const int b   = blockIdx.x >> 3;
    const int dt  = blockIdx.x & 7;
    const int tid = threadIdx.x;
    const int dl  = tid & (DT - 1);
    const int sub = tid >> 4;
    const int d   = dt * DT + dl;

    __shared__ float cP[SUBS][DT], cQ[SUBS][DT], ent[SUBS][DT];
    __shared__ float sPa[NCH], sQa[NCH];

    // sweep 1: local composite over this thread's 16 chunks (kept in regs)
    const int ch0 = sub * CPS;
    const size_t base = ((size_t)b * NCH + ch0) * DD + d;
    float Pr[CPS], Qr[CPS];
    float p = 1.f, q = 0.f;
#pragma unroll
    for (int i = 0; i < CPS; ++i) {
        Pr[i] = Pbuf[base + (size_t)i * DD];
        Qr[i] = Qbuf[base + (size_t)i * DD];
        q = Pr[i] * q + Qr[i];
        p = Pr[i] * p;
    }
    cP[sub][dl] = p; cQ[sub][dl] = q;
    __syncthreads();

    // combine: entry state per sub-range (init state = 0)
    if (tid < DT) {
        float s = 0.f;
#pragma unroll
        for (int sb = 0; sb < SUBS; ++sb) {
            ent[sb][tid] = s;
            s = cP[sb][tid] * s + cQ[sb][tid];
        }
    }
    __syncthreads();

    // sweep 2: replay from entry state, write bst0
    float s = ent[sub][dl];
#pragma unroll
    for (int i = 0; i < CPS; ++i) {
        bst0[base + (size_t)i * DD] = s;
        s = Pr[i] * s + Qr[i];
    }

    // scalar a-scan (one tile of blocks only; block-uniform branch)
    if (dt == 0) {
        float pa = PaBuf[b * NCH + tid];
        float qa = QaBuf[b * NCH + tid];
#pragma unroll
        for (int off = 1; off < NCH; off <<= 1) {
            sPa[tid] = pa; sQa[tid] = qa;
            __syncthreads();
            if (tid >= off) {
                const float pp = sPa[tid - off], qq = sQa[tid - off];
                qa = pa * qq + qa;
                pa = pa * pp;
            }
            __syncthreads();
        }
        sQa[tid] = qa;
        __syncthreads();
        a0[b * NCH + tid] = (tid == 0) ? 0.f : sQa[tid - 1];
    }
}

// ---------------------------------------------------------------------------
// Pass 3: stage the (decay,T) side-band (16 uint2 loads) behind a load fence,
// replay from entry state, fused LayerNorm. No V re-read.
// ---------------------------------------------------------------------------
__global__ __launch_bounds__(NTHR, 4) void pass3_kernel(
    const unsigned* __restrict__ DTb,
    const float* __restrict__ lnw, const float* __restrict__ lnb,
    const float* __restrict__ bst0, const float* __restrict__ a0,
    const float2* __restrict__ MEbuf,
    float* __restrict__ out)
{
    const int wv   = threadIdx.x >> 6;
    const int lane = threadIdx.x & 63;
    const int gc   = blockIdx.x * WPB + wv;
    const int b    = gc >> 8;
    const int ch   = gc & (NCH - 1);
    const int d2   = lane << 1;

    const int t0 = ch * TT;
    const size_t base = ((size_t)b * SS + t0) * DD + d2;
    const uint2* DTp = (const uint2*)(DTb + base);
    float2* Op = (float2*)(out + base);

    // ---- staged bulk load: 16 side-band loads + state, all in flight ----
    uint2 dtR[TT];
#pragma unroll
    for (int t = 0; t < TT; ++t) dtR[t] = DTp[t * (DD / 2)];
    const float2 me = MEbuf[(size_t)b * SS + t0 + (lane & (TT - 1))];
    float2 bst = *(const float2*)(bst0 + (size_t)gc * DD + d2);
    const float a_in = a0[gc];
    const float2 gw = *(const float2*)(lnw + d2);
    const float2 gb = *(const float2*)(lnb + d2);
    LOAD_FENCE();

    float a = a_in;

#pragma unroll
    for (int t = 0; t < TT; ++t) {
        const float mt = __int_as_float(__builtin_amdgcn_readlane(__float_as_int(me.x), t));
        const float et = __int_as_float(__builtin_amdgcn_readlane(__float_as_int(me.y), t));

        a = mt * a + et;
        bst.x = up_lo(dtR[t].x) * bst.x + up_hi(dtR[t].x);
        bst.y = up_lo(dtR[t].y) * bst.y + up_hi(dtR[t].y);

        const float inva = fast_rcp(a + REC_EPS);
        float2 o;
        o.x = bst.x * inva; o.y = bst.y * inva;

        float s1 = o.x + o.y;
        float s2 = o.x * o.x + o.y * o.y;
        wave_red2(s1, s2);
        const float mu  = s1 * (1.0f / DD);
        const float var = s2 * (1.0f / DD) - mu * mu;
        const float rs  = rsqrtf(var + LN_EPS);

        float2 r;
        r.x = (o.x - mu) * rs * gw.x + gb.x;
        r.y = (o.y - mu) * rs * gw.y + gb.y;
        Op[t * (DD / 2)] = r;
    }
}

extern "C" void kernel_launch(void* const* d_in, const int* in_sizes, int n_in,
                              void* d_out, int out_size, void* d_ws, size_t ws_size,
                              hipStream_t stream)
{
    const float* C    = (const float*)d_in[0];
    const float* V    = (const float*)d_in[1];
    const float* W    = (const float*)d_in[2];
    const float* enc  = (const float*)d_in[3];
    const float* tmod = (const float*)d_in[4];
    const float* cmod = (const float*)d_in[5];
    const float* lnw  = (const float*)d_in[6];
    const float* lnb  = (const float*)d_in[7];
    float* out = (float*)d_out;

    // Workspace layout: DT side-band (33.5 MB) + scan buffers (~7 MB)
    float* ws    = (float*)d_ws;
    unsigned* DTbuf = (unsigned*)ws;                      // BB*SS*DD uints
    float* Pbuf  = ws    + (size_t)BB * SS * DD;          // BB*NCH*DD
    float* Qbuf  = Pbuf  + (size_t)BB * NCH * DD;
    float* bst0  = Qbuf  + (size_t)BB * NCH * DD;
    float2* MEbuf = (float2*)(bst0 + (size_t)BB * NCH * DD);  // BB*SS float2
    float* PaBuf = (float*)(MEbuf + (size_t)BB * SS);         // BB*NCH
    float* QaBuf = PaBuf + (size_t)BB * NCH;
    float* a0Buf = QaBuf + (size_t)BB * NCH;

    const int nblk = BB * NCH / WPB;   // 1024
    pass1_kernel<<<nblk, NTHR, 0, stream>>>(C, V, W, enc, tmod, cmod, DTbuf,
                                            Pbuf, Qbuf, PaBuf, QaBuf, MEbuf);
    pass2_kernel<<<BB * 8, 256, 0, stream>>>(Pbuf, Qbuf, PaBuf, QaBuf, bst0, a0Buf);
    pass3_kernel<<<nblk, NTHR, 0, stream>>>(DTbuf, lnw, lnb,
                                            bst0, a0Buf, MEbuf, out);
}